// Round 2
// 217.091 us; speedup vs baseline: 1.2670x; 1.2670x over previous
//
#include <hip/hip_runtime.h>
#include <stdint.h>

// SeqAttnMatch: B=32, LP=2048, LQ=512, D=256, fp32 in/out. Single-plane fp16 pipeline.
#define B_  32
#define LP_ 2048
#define LQ_ 512
#define D_  256

typedef __attribute__((ext_vector_type(8))) short short8;      // 8 x 16-bit
typedef __attribute__((ext_vector_type(8))) _Float16 f16x8;    // MFMA A/B frag (4 VGPRs)
typedef __attribute__((ext_vector_type(4))) float f32x4;

__device__ __forceinline__ ushort f2h(float x) {
    union { _Float16 h; ushort u; } v;
    v.h = (_Float16)x;                 // RNE convert
    return v.u;
}
// async global->LDS, 16B/lane; HW writes lds_base + lane*16 (wave-uniform base).
__device__ __forceinline__ void gl_lds16(const void* g, void* l) {
    __builtin_amdgcn_global_load_lds(
        (const __attribute__((address_space(1))) void*)g,
        (__attribute__((address_space(3))) void*)l, 16, 0, 0);
}

// Fragment-blocked layout: 1KB blocks of 512 ushorts. Element for lane
// L=quad*16+c, position L*8 + j, holds M[row_tile*16 + c][k0 + quad*8 + j].

// ---- K0: fused W f32->f16 frag convert (blocks 0..255) + y transpose (256..767) ----
// W block (kc=k/32, nt=e/16) at kc*16+nt. y block (b, qc=q/32, nt=d/16) at b*256+qc*16+nt,
// lane (c,quad,j) = y[qc*32+quad*8+j][nt*16+c] (Phase-C B operand: k=q, n=d).
__global__ void k_prep(const float* __restrict__ W, const float* __restrict__ y,
                       ushort* __restrict__ Whf, ushort* __restrict__ yf) {
    __shared__ float t[32 * 260];
    if (blockIdx.x < 256) {
        int i = blockIdx.x * 256 + threadIdx.x;
        int e = i >> 8, k = i & 255;
        size_t off = (size_t)((k >> 5) * 16 + (e >> 4)) * 512 +
                     ((k >> 3) & 3) * 128 + (e & 15) * 8 + (k & 7);
        Whf[off] = f2h(W[i]);
        return;
    }
    int bid = blockIdx.x - 256;      // 512 blocks
    int b = bid >> 4, qc = bid & 15;
    int tid = threadIdx.x;
    int ql = tid >> 3;               // 0..31
    int d0 = (tid & 7) * 4;
#pragma unroll
    for (int p = 0; p < 8; p++) {
        int d = p * 32 + d0;
        float4 v = *(const float4*)(y + ((size_t)(b * LQ_ + qc * 32 + ql) * 256 + d));
        t[ql * 260 + d + 0] = v.x; t[ql * 260 + d + 1] = v.y;
        t[ql * 260 + d + 2] = v.z; t[ql * 260 + d + 3] = v.w;
    }
    __syncthreads();
    int w = tid >> 6, L = tid & 63, c = L & 15, quad = L >> 4;
#pragma unroll
    for (int ii = 0; ii < 4; ii++) {
        int nt = w * 4 + ii;
        short8 o;
#pragma unroll
        for (int j = 0; j < 8; j++)
            o[j] = (short)f2h(t[(quad * 8 + j) * 260 + nt * 16 + c]);
        *(short8*)(yf + ((size_t)(b * 256 + qc * 16 + nt) * 512 + L * 8)) = o;
    }
}

// ---- K1: proj = relu(A @ W^T + b) -> frag-blocked f16, single plane ----
// 1280 blocks: 0..255 y-proj, 256..1279 x-proj. 256 thr (4 waves), 64 rows/block.
// x layout: block = rt_g*8 + ec. y layout: (rt_g>>5)*256 + ec*32 + (rt_g&31).
__global__ __launch_bounds__(256, 3) void k_proj(const float* __restrict__ x,
                                                 const float* __restrict__ y,
                                                 const ushort* __restrict__ Whf,
                                                 const float* __restrict__ bias,
                                                 ushort* __restrict__ Ox,
                                                 ushort* __restrict__ Oy) {
    __shared__ __align__(16) ushort Ws[16704];   // 32KB ping-pong, then 33.3KB transpose
    const int tid  = threadIdx.x;
    const int w    = tid >> 6;
    const int L    = tid & 63;
    const int c    = L & 15;
    const int quad = L >> 4;
    const bool isY = blockIdx.x < 256;
    const float* A = isY ? y : x;
    ushort* O      = isY ? Oy : Ox;
    const int blk0 = isY ? blockIdx.x : (blockIdx.x - 256);
    const int row0 = blk0 * 64 + w * 16;
    const int arow = row0 + c;

    f32x4 acc[16];
#pragma unroll
    for (int i = 0; i < 16; i++) acc[i] = (f32x4)0.f;

    // stage unit kc: 16KB W slab (16 x 1KB units), contiguous DMA, 4 units/wave
#define PSTAGE(kc, p)                                                          \
    {                                                                          \
        _Pragma("unroll")                                                      \
        for (int ii = 0; ii < 4; ii++) {                                       \
            int i = w * 4 + ii;                                                \
            gl_lds16(Whf + (size_t)(kc) * 8192 + i * 512 + L * 8,              \
                     (char*)Ws + (p) * 16384 + i * 1024);                      \
        }                                                                      \
    }

    PSTAGE(0, 0);
    float4 nx0 = *(const float4*)(A + (size_t)arow * 256 + quad * 8);
    float4 nx1 = *(const float4*)(A + (size_t)arow * 256 + quad * 8 + 4);

    for (int kc = 0; kc < 8; kc++) {
        __syncthreads();
        if (kc < 7) PSTAGE(kc + 1, (kc + 1) & 1);
        float4 cx0 = nx0, cx1 = nx1;
        if (kc < 7) {
            nx0 = *(const float4*)(A + (size_t)arow * 256 + (kc + 1) * 32 + quad * 8);
            nx1 = *(const float4*)(A + (size_t)arow * 256 + (kc + 1) * 32 + quad * 8 + 4);
        }
        float xs[8] = {cx0.x, cx0.y, cx0.z, cx0.w, cx1.x, cx1.y, cx1.z, cx1.w};
        f16x8 ah;
#pragma unroll
        for (int j = 0; j < 8; j++) ah[j] = (_Float16)xs[j];
        const ushort* buf = Ws + (kc & 1) * 8192;
#pragma unroll
        for (int nt = 0; nt < 16; nt++) {
            f16x8 bh = *(const f16x8*)(buf + nt * 512 + L * 8);
            acc[nt] = __builtin_amdgcn_mfma_f32_16x16x32_f16(ah, bh, acc[nt], 0, 0, 0);
        }
    }

    // epilogue: bias+relu, per-wave LDS transpose C-layout -> A-frag layout
    __syncthreads();                 // all waves done reading Ws
    float* tr = (float*)Ws + w * (16 * 130);
    const int rt_g = row0 >> 4;
#pragma unroll
    for (int half = 0; half < 2; half++) {
#pragma unroll
        for (int nt8 = 0; nt8 < 8; nt8++) {
            int nt = half * 8 + nt8;
            float bv = bias[nt * 16 + c];
#pragma unroll
            for (int r = 0; r < 4; r++)
                tr[(quad * 4 + r) * 130 + nt8 * 16 + c] = fmaxf(acc[nt][r] + bv, 0.f);
        }
#pragma unroll
        for (int ec4 = 0; ec4 < 4; ec4++) {
            int ec = half * 4 + ec4;
            short8 hh;
#pragma unroll
            for (int j = 0; j < 8; j++)
                hh[j] = (short)f2h(tr[c * 130 + ec4 * 32 + quad * 8 + j]);
            size_t blk = isY ? ((size_t)(rt_g >> 5) * 256 + ec * 32 + (rt_g & 31))
                             : ((size_t)rt_g * 8 + ec);
            *(short8*)(O + blk * 512 + L * 8) = hh;
        }
    }
}

// ---- K2: fused scores (f16) + softmax + match (f16). 32 rows/block, 2048 blocks. ----
// Phase A: wave w = q-quarter w, ALL 32 rows, barrier-free; x-frags in LDS (16KB).
// Phase C: all waves sweep full q, wave w = d-quarter -> no partial-sum exchange.
__global__ __launch_bounds__(256, 3) void k_attn(const ushort* __restrict__ xpf,
                                                 const ushort* __restrict__ ypf,
                                                 const ushort* __restrict__ yf,
                                                 float* __restrict__ out) {
    __shared__ __align__(16) ushort lds[16384];   // 32KB
    const int tid  = threadIdx.x;
    const int w    = tid >> 6;
    const int L    = tid & 63;
    const int c    = L & 15;
    const int quad = L >> 4;

    // XCD-affinity swizzle: XCD x sees only batches 4x..4x+3
    const int bid = blockIdx.x;
    const int jj  = bid >> 3;
    const int b   = (bid & 7) * 4 + (jj >> 6);
    const int mt  = jj & 63;                       // 0..63, 32 rows each
    const int m0  = mt * 32;

    // ---- stage x-frags: 16 units (rs*8+kc) x 1KB, contiguous DMA ----
#pragma unroll
    for (int ii = 0; ii < 4; ii++) {
        int unit = w * 4 + ii;
        int rs = unit >> 3, kc = unit & 7;
        gl_lds16(xpf + ((size_t)(b * 128 + mt * 2 + rs) * 8 + kc) * 512 + L * 8,
                 (char*)lds + unit * 1024);
    }

    f32x4 sc[2][8];
#pragma unroll
    for (int rs = 0; rs < 2; rs++)
#pragma unroll
        for (int qt = 0; qt < 8; qt++) sc[rs][qt] = (f32x4)0.f;
    __syncthreads();                 // x-frags visible; ONLY barrier before softmax

    // ---- Phase A: barrier-free; B-frags coalesced from L2-resident ypf ----
    const ushort* yb = ypf + (size_t)b * 256 * 512;
    for (int kc = 0; kc < 8; kc++) {
        f16x8 ah0 = *(const f16x8*)(lds + kc * 512 + L * 8);
        f16x8 ah1 = *(const f16x8*)(lds + (8 + kc) * 512 + L * 8);
#pragma unroll
        for (int qt = 0; qt < 8; qt++) {
            f16x8 bh = *(const f16x8*)(yb + ((size_t)kc * 32 + w * 8 + qt) * 512 + L * 8);
            sc[0][qt] = __builtin_amdgcn_mfma_f32_16x16x32_f16(ah0, bh, sc[0][qt], 0, 0, 0);
            sc[1][qt] = __builtin_amdgcn_mfma_f32_16x16x32_f16(ah1, bh, sc[1][qt], 0, 0, 0);
        }
    }

    // ---- Phase B: softmax; each wave holds a q-quarter of every row ----
    __syncthreads();                 // x-frag reads done; lds reusable
    float* red  = (float*)lds;       // [32][4] partial max
    float* red2 = red + 128;         // [32][4] partial sum
    float inv[2][4];
#pragma unroll
    for (int rs = 0; rs < 2; rs++)
#pragma unroll
        for (int r = 0; r < 4; r++) {
            float pm = sc[rs][0][r];
#pragma unroll
            for (int qt = 1; qt < 8; qt++) pm = fmaxf(pm, sc[rs][qt][r]);
#pragma unroll
            for (int mask = 1; mask <= 8; mask <<= 1) pm = fmaxf(pm, __shfl_xor(pm, mask));
            if (c == 0) red[(rs * 16 + quad * 4 + r) * 4 + w] = pm;
        }
    __syncthreads();
#pragma unroll
    for (int rs = 0; rs < 2; rs++)
#pragma unroll
        for (int r = 0; r < 4; r++) {
            int row = rs * 16 + quad * 4 + r;
            float m = fmaxf(fmaxf(red[row * 4], red[row * 4 + 1]),
                            fmaxf(red[row * 4 + 2], red[row * 4 + 3]));
            float ps = 0.f;
#pragma unroll
            for (int qt = 0; qt < 8; qt++) {
                float e = __expf(sc[rs][qt][r] - m);
                sc[rs][qt][r] = e;
                ps += e;
            }
#pragma unroll
            for (int mask = 1; mask <= 8; mask <<= 1) ps += __shfl_xor(ps, mask);
            if (c == 0) red2[row * 4 + w] = ps;
        }
    __syncthreads();
#pragma unroll
    for (int rs = 0; rs < 2; rs++)
#pragma unroll
        for (int r = 0; r < 4; r++) {
            int row = rs * 16 + quad * 4 + r;
            inv[rs][r] = 1.f / (red2[row * 4] + red2[row * 4 + 1] +
                                red2[row * 4 + 2] + red2[row * 4 + 3]);
        }
    __syncthreads();                 // red/red2 reads done before alpha overwrites

    // alpha (f16) -> LDS [32 rows][512 q], xor-swizzled 8-elem chunks
#pragma unroll
    for (int rs = 0; rs < 2; rs++)
#pragma unroll
        for (int r = 0; r < 4; r++) {
            int m_loc = rs * 16 + quad * 4 + r;
            int swz = m_loc & 7;
            float iv = inv[rs][r];
#pragma unroll
            for (int qt = 0; qt < 8; qt++) {
                int q = w * 128 + qt * 16 + c;
                lds[m_loc * 512 + (((q >> 3) ^ swz) << 3) + (c & 7)] = f2h(sc[rs][qt][r] * iv);
            }
        }
    __syncthreads();

    // ---- Phase C: out = alpha(LDS) @ yf(global). wave w = d-quarter, full q sweep. ----
    f32x4 o[2][4];
#pragma unroll
    for (int rs = 0; rs < 2; rs++)
#pragma unroll
        for (int dt = 0; dt < 4; dt++) o[rs][dt] = (f32x4)0.f;
    const int dh = w;
    const int swzA = c & 7;          // (rs*16+c)&7 == c&7
    for (int kcq = 0; kcq < 16; kcq++) {
        int chunk = kcq * 4 + quad;
        f16x8 af0 = *(const f16x8*)(lds + c * 512 + ((chunk ^ swzA) << 3));
        f16x8 af1 = *(const f16x8*)(lds + (16 + c) * 512 + ((chunk ^ swzA) << 3));
        const ushort* ybf = yf + ((size_t)(b * 256 + kcq * 16 + dh * 4)) * 512;
#pragma unroll
        for (int dt = 0; dt < 4; dt++) {
            f16x8 bfr = *(const f16x8*)(ybf + dt * 512 + L * 8);
            o[0][dt] = __builtin_amdgcn_mfma_f32_16x16x32_f16(af0, bfr, o[0][dt], 0, 0, 0);
            o[1][dt] = __builtin_amdgcn_mfma_f32_16x16x32_f16(af1, bfr, o[1][dt], 0, 0, 0);
        }
    }

    // ---- direct store (no exchange: each wave owns a d-quarter, full q summed) ----
#pragma unroll
    for (int rs = 0; rs < 2; rs++)
#pragma unroll
        for (int dt = 0; dt < 4; dt++)
#pragma unroll
            for (int r = 0; r < 4; r++) {
                int row = rs * 16 + quad * 4 + r;
                out[(size_t)(b * LP_ + m0 + row) * 256 + dh * 64 + dt * 16 + c] =
                    o[rs][dt][r];
            }
}

extern "C" void kernel_launch(void* const* d_in, const int* in_sizes, int n_in,
                              void* d_out, int out_size, void* d_ws, size_t ws_size,
                              hipStream_t stream) {
    const float* x    = (const float*)d_in[0];
    const float* y    = (const float*)d_in[1];
    const float* W    = (const float*)d_in[2];
    const float* bias = (const float*)d_in[3];
    float* out = (float*)d_out;

    char* ws = (char*)d_ws;
    size_t off = 0;
    ushort* Whf = (ushort*)(ws + off); off += (size_t)D_ * D_ * 2;          // 128KB
    ushort* yfb = (ushort*)(ws + off); off += (size_t)B_ * D_ * LQ_ * 2;    // 8MB
    ushort* ypf = (ushort*)(ws + off); off += (size_t)B_ * LQ_ * D_ * 2;    // 8MB
    ushort* xpf = (ushort*)(ws + off); off += (size_t)B_ * LP_ * D_ * 2;    // 32MB

    k_prep<<<768, 256, 0, stream>>>(W, y, Whf, yfb);
    k_proj<<<1280, 256, 0, stream>>>(x, y, Whf, bias, xpf, ypf);
    k_attn<<<B_ * 64, 256, 0, stream>>>(xpf, ypf, yfb, out);
}